// Round 17
// baseline (313.431 us; speedup 1.0000x reference)
//
#include <hip/hip_runtime.h>
#include <math.h>

#define B 8
#define Cc 256
#define P 4096
#define NW 64
#define NH 8
#define HD 32
#define TOPK 4
#define SCALE 0.17677669529663687f
#define EXP2S 0.2550348640579426f   // SCALE * log2(e)

typedef unsigned short u16;
typedef __attribute__((ext_vector_type(4))) float f32x4;
typedef __attribute__((ext_vector_type(8))) short s16x8;
typedef __attribute__((ext_vector_type(4))) unsigned short u16x4;

#define MFMA(a, b, c) __builtin_amdgcn_mfma_f32_16x16x32_bf16(a, b, c, 0, 0, 0)

__device__ inline u16 f2bf(float f) {
  unsigned u = __float_as_uint(f);
  return (u16)((u + 0x7fffu + ((u >> 16) & 1u)) >> 16);
}
__device__ inline float bf2f(u16 h) { return __uint_as_float(((unsigned)h) << 16); }

// ---------------------------------------------------------------------------
// pack v3 + fused weight-convert (blockIdx.z==4 plane)
// ---------------------------------------------------------------------------
__global__ __launch_bounds__(256) void pack_kernel(
    const float* __restrict__ x, const float* __restrict__ prompt,
    const float* __restrict__ Wq, const float* __restrict__ Wk,
    const float* __restrict__ Wv, const float* __restrict__ Wproj,
    const float* __restrict__ Wg,
    u16* __restrict__ XY, u16* __restrict__ PT, float* __restrict__ Pd,
    u16* __restrict__ Wbf) {
  if (blockIdx.z == 4) {
    int id = blockIdx.y * 64 + blockIdx.x;
    if (id >= 640) return;
    int job = id >> 7;
    const float* src;
    u16* dst;
    int n;
    switch (job) {
      case 0: src = Wq;    dst = Wbf;          n = 65536;  break;
      case 1: src = Wk;    dst = Wbf + 65536;  n = 65536;  break;
      case 2: src = Wv;    dst = Wbf + 131072; n = 65536;  break;
      case 3: src = Wproj; dst = Wbf + 196608; n = 65536;  break;
      default: src = Wg;   dst = Wbf + 262144; n = 131072; break;
    }
    int i = ((id & 127) * 256 + threadIdx.x) * 4;
    if (i < n) {
      float4 v = *(const float4*)(src + i);
      u16x4 o = {f2bf(v.x), f2bf(v.y), f2bf(v.z), f2bf(v.w)};
      *(u16x4*)(dst + i) = o;
    }
    return;
  }
  __shared__ u16 ldsd[64 * 68];
  __shared__ float pdl[64 * 9];
  int y = blockIdx.x;
  int sb = blockIdx.y;
  int cq = blockIdx.z;
  int sel = sb >> 3, b = sb & 7;
  const float* src =
      (sel ? prompt : x) + (size_t)(b * 256 + cq * 64) * 4096 + y * 64;
  int tid = threadIdx.x;
  int pxg = tid & 15;
  int cr = tid >> 4;
  int px0 = pxg * 4;
#pragma unroll
  for (int iter = 0; iter < 4; ++iter) {
    int cl = iter * 16 + cr;
    float4 v = *(const float4*)(src + (size_t)cl * 4096 + px0);
    u16x4 o = {f2bf(v.x), f2bf(v.y), f2bf(v.z), f2bf(v.w)};
    int sw = ((cl >> 3) & 3) << 2;
    *(u16x4*)(ldsd + cl * 68 + (px0 ^ sw)) = o;
    float s4 = (v.x + v.y) + (v.z + v.w);
    float s8 = s4 + __shfl_xor(s4, 1);
    if ((pxg & 1) == 0) pdl[cl * 9 + (pxg >> 1)] = s8;
  }
  __syncthreads();
  int tok = tid >> 2, cg = tid & 3;
  int n = ((y >> 3) << 3) + (tok >> 3);
  int tk = ((y & 7) << 3) + (tok & 7);
  size_t prow = (size_t)b * 4096 + n * 64 + tk;
  u16* dst = (sel ? (PT + prow * 256) : (XY + prow * 512)) + cq * 64;
#pragma unroll
  for (int cc = 0; cc < 2; ++cc) {
    int cb = cg * 8 + cc * 32;
    s16x8 v;
#pragma unroll
    for (int j = 0; j < 8; ++j) {
      int cl = cb + j;
      int sw = ((cl >> 3) & 3) << 2;
      v[j] = (short)ldsd[cl * 68 + (tok ^ sw)];
    }
    *(s16x8*)(dst + cb) = v;
  }
  float* pd = Pd + ((size_t)sb * 64 + y) * 2048 + cq * 64;
#pragma unroll
  for (int i = 0; i < 2; ++i) {
    int e = i * 256 + tid;
    int wx = e >> 6, cl = e & 63;
    pd[wx * 256 + cl] = pdl[cl * 9 + wx];
  }
}

// ---------------------------------------------------------------------------
// reduce partials -> descriptors [b][c][n] (f32, deterministic order)
// ---------------------------------------------------------------------------
__global__ __launch_bounds__(256) void dred_kernel(
    const float* __restrict__ Pd, float* __restrict__ dx, float* __restrict__ dp) {
  int sb = blockIdx.x;
  int sel = sb >> 3, b = sb & 7;
  int c = threadIdx.x;
  float* dst = (sel ? dp : dx) + ((size_t)b * 256 + c) * 64;
  const float* src = Pd + (size_t)sb * 64 * 2048;
#pragma unroll
  for (int nn = 0; nn < 8; ++nn) {
    int n = blockIdx.y * 8 + nn;
    int wy = n >> 3, wx = n & 7;
    float s = 0.f;
#pragma unroll
    for (int yl = 0; yl < 8; ++yl)
      s += src[((wy * 8 + yl) * 8 + wx) * 256 + c];
    dst[n] = s * (1.f / 64.f);
  }
}

// ---------------------------------------------------------------------------
// routing (f32, exact)
// ---------------------------------------------------------------------------
__global__ __launch_bounds__(64) void route_kernel(
    const float* __restrict__ dx, const float* __restrict__ dp,
    int* __restrict__ routed) {
  int bq = blockIdx.x;
  int b = bq >> 6;
  int q = bq & 63;
  int lane = threadIdx.x;
  const float* dxb = dx + (size_t)b * Cc * NW;
  const float* dpb = dp + (size_t)b * Cc * NW;
  float s = 0.f;
  for (int c = 0; c < Cc; ++c)
    s = fmaf(dxb[c * NW + q], dpb[c * NW + lane], s);
  s *= (1.f / 16.f);
  for (int kk = 0; kk < TOPK; ++kk) {
    float v = s;
    int i = lane;
    for (int off = 32; off; off >>= 1) {
      float ov = __shfl_xor(v, off);
      int oi = __shfl_xor(i, off);
      if (ov > v || (ov == v && oi < i)) { v = ov; i = oi; }
    }
    if (lane == 0) routed[bq * TOPK + kk] = i;
    if (lane == i) s = -INFINITY;
  }
}

// ---------------------------------------------------------------------------
// MFMA GEMM core 128x128xBK64, reg-staged (R5-proven structure)
// ---------------------------------------------------------------------------
__device__ __forceinline__ void gemm_core(
    const u16* __restrict__ A, int lda, const u16* __restrict__ W, int K,
    int m0, int n0, int tid, u16* Asm, u16* Wsm, f32x4 (&acc)[4][4]) {
  int l = tid & 63, wv = tid >> 6;
  int lq = l & 15, g = l >> 4;
  int wm = (wv & 1) * 64, wn = (wv >> 1) * 64;
  for (int k0 = 0; k0 < K; k0 += 64) {
    s16x8 av[4], wvv[4];
#pragma unroll
    for (int i = 0; i < 4; ++i) {
      int s = i * 256 + tid, row = s >> 3, u = s & 7;
      av[i] = *(const s16x8*)(A + (size_t)(m0 + row) * lda + k0 + u * 8);
      wvv[i] = *(const s16x8*)(W + (size_t)(n0 + row) * K + k0 + u * 8);
    }
    __syncthreads();
#pragma unroll
    for (int i = 0; i < 4; ++i) {
      int s = i * 256 + tid, row = s >> 3, u = s & 7;
      int gu = u ^ (row & 7);
      *(s16x8*)(Asm + row * 64 + gu * 8) = av[i];
      *(s16x8*)(Wsm + row * 64 + gu * 8) = wvv[i];
    }
    __syncthreads();
#pragma unroll
    for (int ks = 0; ks < 2; ++ks) {
      s16x8 af[4], bfr[4];
#pragma unroll
      for (int mi = 0; mi < 4; ++mi) {
        int r = wm + 16 * mi + lq;
        af[mi] = *(const s16x8*)(Asm + r * 64 + ((4 * ks + g) ^ (r & 7)) * 8);
      }
#pragma unroll
      for (int ni = 0; ni < 4; ++ni) {
        int r = wn + 16 * ni + lq;
        bfr[ni] = *(const s16x8*)(Wsm + r * 64 + ((4 * ks + g) ^ (r & 7)) * 8);
      }
#pragma unroll
      for (int mi = 0; mi < 4; ++mi)
#pragma unroll
        for (int ni = 0; ni < 4; ++ni)
          acc[mi][ni] = MFMA(af[mi], bfr[ni], acc[mi][ni]);
    }
  }
}

__device__ __forceinline__ void store_rowmajor(
    f32x4 (&acc)[4][4], u16* __restrict__ Out, int ldo,
    size_t mbase, int nbase, int lq, int g) {
#pragma unroll
  for (int mi = 0; mi < 4; ++mi) {
    size_t mrow = mbase + 16 * mi + 4 * g;
#pragma unroll
    for (int r = 0; r < 4; ++r) {
      u16* orow = Out + (mrow + r) * ldo + nbase + lq;
#pragma unroll
      for (int ni = 0; ni < 4; ++ni)
        orow[16 * ni] = f2bf(acc[mi][ni][r]);
    }
  }
}

__device__ __forceinline__ void store_chanmajor(
    f32x4 (&acc)[4][4], u16* __restrict__ Out,
    int bb, int tb, int cbase, int lq) {
#pragma unroll
  for (int ni = 0; ni < 4; ++ni) {
    u16* ocol = Out + ((size_t)(bb * 256) + cbase + 16 * ni + lq) * 4096 + tb;
#pragma unroll
    for (int mi = 0; mi < 4; ++mi) {
      u16x4 pk = {f2bf(acc[mi][ni][0]), f2bf(acc[mi][ni][1]),
                  f2bf(acc[mi][ni][2]), f2bf(acc[mi][ni][3])};
      *(u16x4*)(ocol + 16 * mi) = pk;
    }
  }
}

// ---------------------------------------------------------------------------
// Q/K/V in one launch: jy<2 -> Q (A=x part of XY); jy 2..5 -> K|V (A=PT)
// ---------------------------------------------------------------------------
__global__ __launch_bounds__(256) void qkv_kernel(
    const u16* __restrict__ XY, const u16* __restrict__ PT,
    const u16* __restrict__ Wbf, u16* __restrict__ QT,
    u16* __restrict__ KT, u16* __restrict__ VT) {
  __shared__ u16 Asm[8192], Wsm[8192];
  int jy = blockIdx.y, m0 = blockIdx.x * 128;
  int tid = threadIdx.x;
  int l = tid & 63, wv = tid >> 6;
  int lq = l & 15, g = l >> 4;
  int wm = (wv & 1) * 64, wn = (wv >> 1) * 64;
  f32x4 acc[4][4];
#pragma unroll
  for (int mi = 0; mi < 4; ++mi)
#pragma unroll
    for (int ni = 0; ni < 4; ++ni)
      acc[mi][ni] = (f32x4){0.f, 0.f, 0.f, 0.f};

  const u16* A;
  const u16* W;
  int lda, n0;
  if (jy < 2) { A = XY; lda = 512; W = Wbf; n0 = jy * 128; }
  else        { A = PT; lda = 256; W = Wbf + 65536; n0 = (jy - 2) * 128; }
  gemm_core(A, lda, W, 256, m0, n0, tid, Asm, Wsm, acc);

  if (jy < 2) {
    store_rowmajor(acc, QT, 256, (size_t)(m0 + wm), n0 + wn, lq, g);
  } else if (n0 < 256) {
    store_rowmajor(acc, KT, 256, (size_t)(m0 + wm), n0 + wn, lq, g);
  } else {
    store_chanmajor(acc, VT, m0 >> 12, (m0 & 4095) + wm + 4 * g,
                    (n0 - 256) + wn, lq);
  }
}

// ---------------------------------------------------------------------------
// gate: G = Wg * [x|y] (A=XY, K=512) + BN partial sums from f32 acc
// ---------------------------------------------------------------------------
__global__ __launch_bounds__(256) void gate_kernel(
    const u16* __restrict__ XY, const u16* __restrict__ Wbf,
    u16* __restrict__ GT, float* __restrict__ pS, float* __restrict__ pSS) {
  __shared__ u16 Asm[8192], Wsm[8192];
  int m0 = blockIdx.x * 128, n0 = blockIdx.y * 128;
  int tid = threadIdx.x;
  int l = tid & 63, wv = tid >> 6;
  int lq = l & 15, g = l >> 4;
  int wm = (wv & 1) * 64, wn = (wv >> 1) * 64;
  f32x4 acc[4][4];
#pragma unroll
  for (int mi = 0; mi < 4; ++mi)
#pragma unroll
    for (int ni = 0; ni < 4; ++ni)
      acc[mi][ni] = (f32x4){0.f, 0.f, 0.f, 0.f};
  gemm_core(XY, 512, Wbf + 262144, 512, m0, n0, tid, Asm, Wsm, acc);
  store_rowmajor(acc, GT, 256, (size_t)(m0 + wm), n0 + wn, lq, g);

  float cs[4], cq[4];
#pragma unroll
  for (int ni = 0; ni < 4; ++ni) {
    float s = 0.f, q2 = 0.f;
#pragma unroll
    for (int mi = 0; mi < 4; ++mi)
#pragma unroll
      for (int r = 0; r < 4; ++r) {
        float v = acc[mi][ni][r];
        s += v;
        q2 = fmaf(v, v, q2);
      }
    cs[ni] = s;
    cq[ni] = q2;
  }
#pragma unroll
  for (int ni = 0; ni < 4; ++ni) {
    cs[ni] += __shfl_xor(cs[ni], 16);
    cs[ni] += __shfl_xor(cs[ni], 32);
    cq[ni] += __shfl_xor(cq[ni], 16);
    cq[ni] += __shfl_xor(cq[ni], 32);
  }
  float* sS = (float*)Asm;
  float* sQ = sS + 128;
  __syncthreads();
  if ((wv & 1) == 0 && g == 0) {
#pragma unroll
    for (int ni = 0; ni < 4; ++ni) {
      int col = wn + 16 * ni + lq;
      sS[col] = cs[ni];
      sQ[col] = cq[ni];
    }
  }
  __syncthreads();
  if ((wv & 1) == 1 && g == 0) {
#pragma unroll
    for (int ni = 0; ni < 4; ++ni) {
      int col = wn + 16 * ni + lq;
      sS[col] += cs[ni];
      sQ[col] += cq[ni];
    }
  }
  __syncthreads();
  if (tid < 128) {
    pS[(size_t)blockIdx.x * 256 + n0 + tid] = sS[tid];
    pSS[(size_t)blockIdx.x * 256 + n0 + tid] = sQ[tid];
  }
}

// ---------------------------------------------------------------------------
// MFMA attention + fused proj, split-K across wave halves.
// 16 waves: wave (h, half) does 2 routed windows for head h (R15 body).
// Combine: half1 -> f32 LDS tile [64][260] + denom buf; half0 adds in regs.
// Then R15 O-tile write (half0) and 16-way proj (16 cols/wave).
// ---------------------------------------------------------------------------
__global__ __launch_bounds__(1024, 8) void attn_kernel(
    const u16* __restrict__ Qb, const u16* __restrict__ Kb,
    const u16* __restrict__ Vt, const int* __restrict__ routed,
    const u16* __restrict__ Wp, u16* __restrict__ XY) {
  __shared__ char Plds[81920];   // 16 waves x 64 q x 80B
  int bn = blockIdx.x, b = bn >> 6, n = bn & 63;
  int wid = threadIdx.x >> 6;    // 0..15
  int h = wid & 7, half = wid >> 3;
  int l = threadIdx.x & 63;
  int lq = l & 15, g = l >> 4;
  char* Pw = Plds + wid * 5120;

  const u16* Qrow = Qb + ((size_t)(b * 4096) + n * 64) * 256 + h * 32 + g * 8;
  s16x8 qf[4];
#pragma unroll
  for (int qi = 0; qi < 4; ++qi)
    qf[qi] = *(const s16x8*)(Qrow + (16 * qi + lq) * 256);

  f32x4 acc[4][2];
#pragma unroll
  for (int qi = 0; qi < 4; ++qi) {
    acc[qi][0] = (f32x4){0.f, 0.f, 0.f, 0.f};
    acc[qi][1] = (f32x4){0.f, 0.f, 0.f, 0.f};
  }
  float denom[4] = {0.f, 0.f, 0.f, 0.f};
  const f32x4 zero4 = {0.f, 0.f, 0.f, 0.f};
  const int* rptr = routed + bn * TOPK;

#pragma unroll
  for (int kx = 0; kx < 2; ++kx) {
    int pw = __builtin_amdgcn_readfirstlane(rptr[half * 2 + kx]);
    const u16* Krow = Kb + ((size_t)(b * 4096) + pw * 64) * 256 + h * 32 + g * 8;
    const u16* Vrow = Vt + ((size_t)(b * 256) + h * 32 + lq) * 4096 + pw * 64 + 8 * g;
#pragma unroll
    for (int hh = 0; hh < 2; ++hh) {
#pragma unroll
      for (int kvil = 0; kvil < 2; ++kvil) {
        int kvi = hh * 2 + kvil;
        s16x8 kf = *(const s16x8*)(Krow + (16 * kvi + lq) * 256);
        f32x4 sv[4];
#pragma unroll
        for (int qi = 0; qi < 4; ++qi)
          sv[qi] = MFMA(kf, qf[qi], zero4);
#pragma unroll
        for (int qi = 0; qi < 4; ++qi) {
          float p0 = __builtin_amdgcn_exp2f(sv[qi][0] * EXP2S);
          float p1 = __builtin_amdgcn_exp2f(sv[qi][1] * EXP2S);
          float p2 = __builtin_amdgcn_exp2f(sv[qi][2] * EXP2S);
          float p3 = __builtin_amdgcn_exp2f(sv[qi][3] * EXP2S);
          denom[qi] += (p0 + p1) + (p2 + p3);
          uint2 pk;
          pk.x = (unsigned)f2bf(p0) | ((unsigned)f2bf(p1) << 16);
          pk.y = (unsigned)f2bf(p2) | ((unsigned)f2bf(p3) << 16);
          int q = 16 * qi + lq;
          *(uint2*)(Pw + q * 80 + (16 * kvil + 4 * g) * 2) = pk;
        }
      }
      s16x8 vf[2];
#pragma unroll
      for (int di = 0; di < 2; ++di)
        vf[di] = *(const s16x8*)(Vrow + (size_t)(16 * di) * 4096 + 32 * hh);
#pragma unroll
      for (int qi = 0; qi < 4; ++qi) {
        int q = 16 * qi + lq;
        s16x8 pf = *(const s16x8*)(Pw + q * 80 + 16 * g);
#pragma unroll
        for (int di = 0; di < 2; ++di)
          acc[qi][di] = MFMA(pf, vf[di], acc[qi][di]);
      }
    }
  }

#pragma unroll
  for (int qi = 0; qi < 4; ++qi) {
    denom[qi] += __shfl_xor(denom[qi], 16);
    denom[qi] += __shfl_xor(denom[qi], 32);
  }

  // --- combine halves via LDS f32 tile
  __syncthreads();               // all P regions dead
  float* Of = (float*)Plds;      // [64][260] padded
  float* db = (float*)(Plds + 66560);  // [8][64]
  if (half == 1) {
#pragma unroll
    for (int qi = 0; qi < 4; ++qi)
#pragma unroll
      for (int r = 0; r < 4; ++r) {
        int t = 16 * qi + 4 * g + r;
#pragma unroll
        for (int di = 0; di < 2; ++di)
          Of[t * 260 + h * 32 + 16 * di + lq] = acc[qi][di][r];
      }
    if (g == 0) {
#pragma unroll
      for (int qi = 0; qi < 4; ++qi)
        db[h * 64 + 16 * qi + lq] = denom[qi];
    }
  }
  __syncthreads();
  if (half == 0) {
#pragma unroll
    for (int qi = 0; qi < 4; ++qi)
      denom[qi] += db[h * 64 + 16 * qi + lq];
#pragma unroll
    for (int qi = 0; qi < 4; ++qi)
#pragma unroll
      for (int r = 0; r < 4; ++r) {
        int t = 16 * qi + 4 * g + r;
#pragma unroll
        for (int di = 0; di < 2; ++di)
          acc[qi][di][r] += Of[t * 260 + h * 32 + 16 * di + lq];
      }
  }
  __syncthreads();               // all Of/db reads done

  // --- write normalized O (bf16) into LDS tile [64 tok][256 ch], swizzled
  char* Ot = Plds;
  if (half == 0) {
#pragma unroll
    for (int qi = 0; qi < 4; ++qi) {
      float inv = 1.f / denom[qi];
#pragma unroll
      for (int r = 0; r < 4; ++r) {
        float nr = __shfl(inv, 4 * g + r);
        int t = 16 * qi + 4 * g + r;
        char* rowp = Ot + t * 512;
#pragma unroll
        for (int di = 0; di < 2; ++di) {
          int c = h * 32 + 16 * di + lq;
          *(u16*)(rowp + ((c * 2) ^ ((t & 7) << 4))) =
              f2bf(acc[qi][di][r] * nr);
        }
      }
    }
  }
  __syncthreads();

  // --- fused proj: 16 waves, wave (h,half) computes 16 Y cols
  int cb = h * 32 + half * 16;
  f32x4 acc2[4];
#pragma unroll
  for (int mi = 0; mi < 4; ++mi)
    acc2[mi] = (f32x4){0.f, 0.f, 0.f, 0.f};
#pragma unroll
  for (int k0 = 0; k0 < 256; k0 += 32) {
    s16x8 af[4];
#pragma unroll
    for (int mi = 0; mi < 4; ++mi) {
      int t = 16 * mi + lq;
      af[mi] = *(const s16x8*)(Ot + t * 512 +
                               (((k0 + 8 * g) * 2) ^ ((t & 7) << 4)));
    }
    s16x8 bfr = *(const s16x8*)(Wp + (size_t)(cb + lq) * 256 + k0 + 8 * g);
#pragma unroll
    for (int mi = 0; mi < 4; ++mi)
      acc2[mi] = MFMA(af[mi], bfr, acc2[mi]);
  }

  u16* Yrow = XY + ((size_t)(b * 4096) + n * 64) * 512 + 256 + cb;
#pragma unroll
  for (int mi = 0; mi < 4; ++mi)
#pragma unroll
    for (int r = 0; r < 4; ++r)
      Yrow[(size_t)(16 * mi + 4 * g + r) * 512 + lq] = f2bf(acc2[mi][r]);
}

// ---------------------------------------------------------------------------
// BN finalize: sum 256 block-partials per channel -> scale/shift
// ---------------------------------------------------------------------------
__global__ __launch_bounds__(1024) void bnfin_kernel(
    const float* __restrict__ pS, const float* __restrict__ pSS,
    const float* __restrict__ gamma, const float* __restrict__ beta,
    float* __restrict__ scale, float* __restrict__ shift) {
  int tid = threadIdx.x;
  int c = tid >> 2, part = tid & 3;
  float S = 0.f, SS = 0.f;
  for (int m = part * 64; m < part * 64 + 64; ++m) {
    S += pS[m * 256 + c];
    SS += pSS[m * 256 + c];
  }
  __shared__ float rS[4][256], rQ[4][256];
  rS[part][c] = S;
  rQ[part][c] = SS;
  __syncthreads();
  if (tid < 256) {
    int cc = tid;
    float S2 = rS[0][cc] + rS[1][cc] + rS[2][cc] + rS[3][cc];
    float Q2 = rQ[0][cc] + rQ[1][cc] + rQ[2][cc] + rQ[3][cc];
    const float invN = 1.f / 32768.f;
    float mean = S2 * invN;
    float var = Q2 * invN - mean * mean;
    float sc = rsqrtf(var + 1e-5f) * gamma[cc];
    scale[cc] = sc;
    shift[cc] = beta[cc] - mean * sc;
  }
}

// ---------------------------------------------------------------------------
// final: block = (image row y, b). LDS-stage Y,G token-major; compute phase
// lane = pixel -> coalesced x/out.
// ---------------------------------------------------------------------------
__global__ __launch_bounds__(256) void final_kernel(
    const float* __restrict__ x, const u16* __restrict__ XY,
    const u16* __restrict__ GT, const float* __restrict__ scale,
    const float* __restrict__ shift, float* __restrict__ out) {
  __shared__ u16 Yl[64 * 256];
  __shared__ u16 Gl[64 * 256];
  __shared__ float sSc[256], sSh[256];
  int y = blockIdx.x, b = blockIdx.y;
  int tid = threadIdx.x;
  sSc[tid] = scale[tid];
  sSh[tid] = shift[tid];
  {
    int r = tid >> 2;
    int n = ((y >> 3) << 3) + (r >> 3);
    int t = ((y & 7) << 3) + (r & 7);
    size_t prow = (size_t)b * 4096 + n * 64 + t;
    const u16* ysrc = XY + prow * 512 + 256;
    const u16* gsrc = GT + prow * 256;
#pragma unroll
    for (int cc = 0; cc < 8; ++cc) {
      int chunk = (tid & 3) * 8 + cc;
      int off = r * 256 + ((chunk ^ (r & 31)) << 3);
      *(s16x8*)(Yl + off) = *(const s16x8*)(ysrc + chunk * 8);
      *(s16x8*)(Gl + off) = *(const s16x8*)(gsrc + chunk * 8);
    }
  }
  __syncthreads();
  int lane = tid & 63, wq = tid >> 6;
  size_t base = (size_t)(b * 256) * 4096 + y * 64 + lane;
#pragma unroll 2
  for (int ch = 0; ch < 8; ++ch) {
    int chunk = wq * 8 + ch;
    int off = lane * 256 + ((chunk ^ (lane & 31)) << 3);
    s16x8 yv = *(const s16x8*)(Yl + off);
    s16x8 gv = *(const s16x8*)(Gl + off);
#pragma unroll
    for (int j = 0; j < 8; ++j) {
      int c = chunk * 8 + j;
      size_t a = base + (size_t)c * 4096;
      float gate = 1.f / (1.f + __expf(-fmaf(bf2f((u16)gv[j]), sSc[c], sSh[c])));
      out[a] = x[a] + gate * bf2f((u16)yv[j]);
    }
  }
}

// ---------------------------------------------------------------------------
extern "C" void kernel_launch(void* const* d_in, const int* in_sizes, int n_in,
                              void* d_out, int out_size, void* d_ws, size_t ws_size,
                              hipStream_t stream) {
  const float* x      = (const float*)d_in[0];
  const float* prompt = (const float*)d_in[1];
  const float* Wq     = (const float*)d_in[2];
  const float* Wk     = (const float*)d_in[3];
  const float* Wv     = (const float*)d_in[4];
  const float* Wproj  = (const float*)d_in[5];
  const float* Wg     = (const float*)d_in[6];
  const float* gamma  = (const float*)d_in[7];
  const float* beta   = (const float*)d_in[8];

  char* wsb = (char*)d_ws;
  u16* XY    = (u16*)(wsb + 0);           // [b][p'][512]: x | y
  u16* PT    = (u16*)(wsb + 33554432);    // prompt [b][p'][256]
  u16* QT    = (u16*)(wsb + 50331648);    // Q [b][p'][256]  (aliases Pd, GT)
  u16* KT    = (u16*)(wsb + 67108864);    // K [b][p'][256]  (aliases pS/pSS)
  u16* VT    = (u16*)(wsb + 83886080);    // V channel-major [b*256+c][4096]
  u16* Wbf   = (u16*)(wsb + 117440512);   // Wq|Wk|Wv|Wproj|Wg bf16
  float* dx  = (float*)(wsb + 118226944);
  float* dp  = (float*)(wsb + 118751232);
  float* scl = (float*)(wsb + 119275520);
  float* shf = (float*)(wsb + 119276544);
  int* routed = (int*)(wsb + 119277568);
  float* Pd  = (float*)QT;                // 8MB, dead before qkv writes QT
  float* pS  = (float*)KT;                // 256KB, after attn (KT dead)
  float* pSS = (float*)(wsb + 67108864 + 262144);
  u16* GT = QT;                           // reuse: Q dead after attention

  pack_kernel<<<dim3(64, 16, 5), 256, 0, stream>>>(
      x, prompt, Wq, Wk, Wv, Wproj, Wg, XY, PT, Pd, Wbf);
  dred_kernel<<<dim3(16, 8), 256, 0, stream>>>(Pd, dx, dp);
  route_kernel<<<B * NW, 64, 0, stream>>>(dx, dp, routed);
  qkv_kernel<<<dim3(256, 6), 256, 0, stream>>>(XY, PT, Wbf, QT, KT, VT);
  attn_kernel<<<B * NW, 1024, 0, stream>>>(QT, KT, VT, routed,
                                           Wbf + 196608, XY);
  gate_kernel<<<dim3(256, 2), 256, 0, stream>>>(XY, Wbf, GT, pS, pSS);
  bnfin_kernel<<<1, 1024, 0, stream>>>(pS, pSS, gamma, beta, scl, shf);
  final_kernel<<<dim3(64, 8), 256, 0, stream>>>(x, XY, GT, scl, shf, (float*)d_out);
}

// Round 18
// 158.158 us; speedup vs baseline: 1.9818x; 1.9818x over previous
//
#include <hip/hip_runtime.h>
#include <math.h>

#define B 8
#define Cc 256
#define P 4096
#define NW 64
#define NH 8
#define HD 32
#define TOPK 4
#define SCALE 0.17677669529663687f
#define EXP2S 0.2550348640579426f   // SCALE * log2(e)

typedef unsigned short u16;
typedef __attribute__((ext_vector_type(4))) float f32x4;
typedef __attribute__((ext_vector_type(8))) short s16x8;
typedef __attribute__((ext_vector_type(4))) unsigned short u16x4;

#define MFMA(a, b, c) __builtin_amdgcn_mfma_f32_16x16x32_bf16(a, b, c, 0, 0, 0)

__device__ inline u16 f2bf(float f) {
  unsigned u = __float_as_uint(f);
  return (u16)((u + 0x7fffu + ((u >> 16) & 1u)) >> 16);
}
__device__ inline float bf2f(u16 h) { return __uint_as_float(((unsigned)h) << 16); }

// ---------------------------------------------------------------------------
// pack v3 + fused weight-convert (blockIdx.z==4 plane)
// ---------------------------------------------------------------------------
__global__ __launch_bounds__(256) void pack_kernel(
    const float* __restrict__ x, const float* __restrict__ prompt,
    const float* __restrict__ Wq, const float* __restrict__ Wk,
    const float* __restrict__ Wv, const float* __restrict__ Wproj,
    const float* __restrict__ Wg,
    u16* __restrict__ XY, u16* __restrict__ PT, float* __restrict__ Pd,
    u16* __restrict__ Wbf) {
  if (blockIdx.z == 4) {
    int id = blockIdx.y * 64 + blockIdx.x;
    if (id >= 640) return;
    int job = id >> 7;
    const float* src;
    u16* dst;
    int n;
    switch (job) {
      case 0: src = Wq;    dst = Wbf;          n = 65536;  break;
      case 1: src = Wk;    dst = Wbf + 65536;  n = 65536;  break;
      case 2: src = Wv;    dst = Wbf + 131072; n = 65536;  break;
      case 3: src = Wproj; dst = Wbf + 196608; n = 65536;  break;
      default: src = Wg;   dst = Wbf + 262144; n = 131072; break;
    }
    int i = ((id & 127) * 256 + threadIdx.x) * 4;
    if (i < n) {
      float4 v = *(const float4*)(src + i);
      u16x4 o = {f2bf(v.x), f2bf(v.y), f2bf(v.z), f2bf(v.w)};
      *(u16x4*)(dst + i) = o;
    }
    return;
  }
  __shared__ u16 ldsd[64 * 68];
  __shared__ float pdl[64 * 9];
  int y = blockIdx.x;
  int sb = blockIdx.y;
  int cq = blockIdx.z;
  int sel = sb >> 3, b = sb & 7;
  const float* src =
      (sel ? prompt : x) + (size_t)(b * 256 + cq * 64) * 4096 + y * 64;
  int tid = threadIdx.x;
  int pxg = tid & 15;
  int cr = tid >> 4;
  int px0 = pxg * 4;
#pragma unroll
  for (int iter = 0; iter < 4; ++iter) {
    int cl = iter * 16 + cr;
    float4 v = *(const float4*)(src + (size_t)cl * 4096 + px0);
    u16x4 o = {f2bf(v.x), f2bf(v.y), f2bf(v.z), f2bf(v.w)};
    int sw = ((cl >> 3) & 3) << 2;
    *(u16x4*)(ldsd + cl * 68 + (px0 ^ sw)) = o;
    float s4 = (v.x + v.y) + (v.z + v.w);
    float s8 = s4 + __shfl_xor(s4, 1);
    if ((pxg & 1) == 0) pdl[cl * 9 + (pxg >> 1)] = s8;
  }
  __syncthreads();
  int tok = tid >> 2, cg = tid & 3;
  int n = ((y >> 3) << 3) + (tok >> 3);
  int tk = ((y & 7) << 3) + (tok & 7);
  size_t prow = (size_t)b * 4096 + n * 64 + tk;
  u16* dst = (sel ? (PT + prow * 256) : (XY + prow * 512)) + cq * 64;
#pragma unroll
  for (int cc = 0; cc < 2; ++cc) {
    int cb = cg * 8 + cc * 32;
    s16x8 v;
#pragma unroll
    for (int j = 0; j < 8; ++j) {
      int cl = cb + j;
      int sw = ((cl >> 3) & 3) << 2;
      v[j] = (short)ldsd[cl * 68 + (tok ^ sw)];
    }
    *(s16x8*)(dst + cb) = v;
  }
  float* pd = Pd + ((size_t)sb * 64 + y) * 2048 + cq * 64;
#pragma unroll
  for (int i = 0; i < 2; ++i) {
    int e = i * 256 + tid;
    int wx = e >> 6, cl = e & 63;
    pd[wx * 256 + cl] = pdl[cl * 9 + wx];
  }
}

// ---------------------------------------------------------------------------
// reduce partials -> descriptors [b][c][n] (f32, deterministic order)
// ---------------------------------------------------------------------------
__global__ __launch_bounds__(256) void dred_kernel(
    const float* __restrict__ Pd, float* __restrict__ dx, float* __restrict__ dp) {
  int sb = blockIdx.x;
  int sel = sb >> 3, b = sb & 7;
  int c = threadIdx.x;
  float* dst = (sel ? dp : dx) + ((size_t)b * 256 + c) * 64;
  const float* src = Pd + (size_t)sb * 64 * 2048;
#pragma unroll
  for (int nn = 0; nn < 8; ++nn) {
    int n = blockIdx.y * 8 + nn;
    int wy = n >> 3, wx = n & 7;
    float s = 0.f;
#pragma unroll
    for (int yl = 0; yl < 8; ++yl)
      s += src[((wy * 8 + yl) * 8 + wx) * 256 + c];
    dst[n] = s * (1.f / 64.f);
  }
}

// ---------------------------------------------------------------------------
// routing (f32, exact)
// ---------------------------------------------------------------------------
__global__ __launch_bounds__(64) void route_kernel(
    const float* __restrict__ dx, const float* __restrict__ dp,
    int* __restrict__ routed) {
  int bq = blockIdx.x;
  int b = bq >> 6;
  int q = bq & 63;
  int lane = threadIdx.x;
  const float* dxb = dx + (size_t)b * Cc * NW;
  const float* dpb = dp + (size_t)b * Cc * NW;
  float s = 0.f;
  for (int c = 0; c < Cc; ++c)
    s = fmaf(dxb[c * NW + q], dpb[c * NW + lane], s);
  s *= (1.f / 16.f);
  for (int kk = 0; kk < TOPK; ++kk) {
    float v = s;
    int i = lane;
    for (int off = 32; off; off >>= 1) {
      float ov = __shfl_xor(v, off);
      int oi = __shfl_xor(i, off);
      if (ov > v || (ov == v && oi < i)) { v = ov; i = oi; }
    }
    if (lane == 0) routed[bq * TOPK + kk] = i;
    if (lane == i) s = -INFINITY;
  }
}

// ---------------------------------------------------------------------------
// MFMA GEMM core 128x128xBK64, reg-staged (R5-proven structure)
// ---------------------------------------------------------------------------
__device__ __forceinline__ void gemm_core(
    const u16* __restrict__ A, int lda, const u16* __restrict__ W, int K,
    int m0, int n0, int tid, u16* Asm, u16* Wsm, f32x4 (&acc)[4][4]) {
  int l = tid & 63, wv = tid >> 6;
  int lq = l & 15, g = l >> 4;
  int wm = (wv & 1) * 64, wn = (wv >> 1) * 64;
  for (int k0 = 0; k0 < K; k0 += 64) {
    s16x8 av[4], wvv[4];
#pragma unroll
    for (int i = 0; i < 4; ++i) {
      int s = i * 256 + tid, row = s >> 3, u = s & 7;
      av[i] = *(const s16x8*)(A + (size_t)(m0 + row) * lda + k0 + u * 8);
      wvv[i] = *(const s16x8*)(W + (size_t)(n0 + row) * K + k0 + u * 8);
    }
    __syncthreads();
#pragma unroll
    for (int i = 0; i < 4; ++i) {
      int s = i * 256 + tid, row = s >> 3, u = s & 7;
      int gu = u ^ (row & 7);
      *(s16x8*)(Asm + row * 64 + gu * 8) = av[i];
      *(s16x8*)(Wsm + row * 64 + gu * 8) = wvv[i];
    }
    __syncthreads();
#pragma unroll
    for (int ks = 0; ks < 2; ++ks) {
      s16x8 af[4], bfr[4];
#pragma unroll
      for (int mi = 0; mi < 4; ++mi) {
        int r = wm + 16 * mi + lq;
        af[mi] = *(const s16x8*)(Asm + r * 64 + ((4 * ks + g) ^ (r & 7)) * 8);
      }
#pragma unroll
      for (int ni = 0; ni < 4; ++ni) {
        int r = wn + 16 * ni + lq;
        bfr[ni] = *(const s16x8*)(Wsm + r * 64 + ((4 * ks + g) ^ (r & 7)) * 8);
      }
#pragma unroll
      for (int mi = 0; mi < 4; ++mi)
#pragma unroll
        for (int ni = 0; ni < 4; ++ni)
          acc[mi][ni] = MFMA(af[mi], bfr[ni], acc[mi][ni]);
    }
  }
}

__device__ __forceinline__ void store_rowmajor(
    f32x4 (&acc)[4][4], u16* __restrict__ Out, int ldo,
    size_t mbase, int nbase, int lq, int g) {
#pragma unroll
  for (int mi = 0; mi < 4; ++mi) {
    size_t mrow = mbase + 16 * mi + 4 * g;
#pragma unroll
    for (int r = 0; r < 4; ++r) {
      u16* orow = Out + (mrow + r) * ldo + nbase + lq;
#pragma unroll
      for (int ni = 0; ni < 4; ++ni)
        orow[16 * ni] = f2bf(acc[mi][ni][r]);
    }
  }
}

__device__ __forceinline__ void store_chanmajor(
    f32x4 (&acc)[4][4], u16* __restrict__ Out,
    int bb, int tb, int cbase, int lq) {
#pragma unroll
  for (int ni = 0; ni < 4; ++ni) {
    u16* ocol = Out + ((size_t)(bb * 256) + cbase + 16 * ni + lq) * 4096 + tb;
#pragma unroll
    for (int mi = 0; mi < 4; ++mi) {
      u16x4 pk = {f2bf(acc[mi][ni][0]), f2bf(acc[mi][ni][1]),
                  f2bf(acc[mi][ni][2]), f2bf(acc[mi][ni][3])};
      *(u16x4*)(ocol + 16 * mi) = pk;
    }
  }
}

// ---------------------------------------------------------------------------
// Q/K/V in one launch: jy<2 -> Q (A=x part of XY); jy 2..5 -> K|V (A=PT)
// ---------------------------------------------------------------------------
__global__ __launch_bounds__(256) void qkv_kernel(
    const u16* __restrict__ XY, const u16* __restrict__ PT,
    const u16* __restrict__ Wbf, u16* __restrict__ QT,
    u16* __restrict__ KT, u16* __restrict__ VT) {
  __shared__ u16 Asm[8192], Wsm[8192];
  int jy = blockIdx.y, m0 = blockIdx.x * 128;
  int tid = threadIdx.x;
  int l = tid & 63, wv = tid >> 6;
  int lq = l & 15, g = l >> 4;
  int wm = (wv & 1) * 64, wn = (wv >> 1) * 64;
  f32x4 acc[4][4];
#pragma unroll
  for (int mi = 0; mi < 4; ++mi)
#pragma unroll
    for (int ni = 0; ni < 4; ++ni)
      acc[mi][ni] = (f32x4){0.f, 0.f, 0.f, 0.f};

  const u16* A;
  const u16* W;
  int lda, n0;
  if (jy < 2) { A = XY; lda = 512; W = Wbf; n0 = jy * 128; }
  else        { A = PT; lda = 256; W = Wbf + 65536; n0 = (jy - 2) * 128; }
  gemm_core(A, lda, W, 256, m0, n0, tid, Asm, Wsm, acc);

  if (jy < 2) {
    store_rowmajor(acc, QT, 256, (size_t)(m0 + wm), n0 + wn, lq, g);
  } else if (n0 < 256) {
    store_rowmajor(acc, KT, 256, (size_t)(m0 + wm), n0 + wn, lq, g);
  } else {
    store_chanmajor(acc, VT, m0 >> 12, (m0 & 4095) + wm + 4 * g,
                    (n0 - 256) + wn, lq);
  }
}

// ---------------------------------------------------------------------------
// gate: G = Wg * [x|y] (A=XY, K=512) + BN partial sums from f32 acc
// ---------------------------------------------------------------------------
__global__ __launch_bounds__(256) void gate_kernel(
    const u16* __restrict__ XY, const u16* __restrict__ Wbf,
    u16* __restrict__ GT, float* __restrict__ pS, float* __restrict__ pSS) {
  __shared__ u16 Asm[8192], Wsm[8192];
  int m0 = blockIdx.x * 128, n0 = blockIdx.y * 128;
  int tid = threadIdx.x;
  int l = tid & 63, wv = tid >> 6;
  int lq = l & 15, g = l >> 4;
  int wm = (wv & 1) * 64, wn = (wv >> 1) * 64;
  f32x4 acc[4][4];
#pragma unroll
  for (int mi = 0; mi < 4; ++mi)
#pragma unroll
    for (int ni = 0; ni < 4; ++ni)
      acc[mi][ni] = (f32x4){0.f, 0.f, 0.f, 0.f};
  gemm_core(XY, 512, Wbf + 262144, 512, m0, n0, tid, Asm, Wsm, acc);
  store_rowmajor(acc, GT, 256, (size_t)(m0 + wm), n0 + wn, lq, g);

  float cs[4], cq[4];
#pragma unroll
  for (int ni = 0; ni < 4; ++ni) {
    float s = 0.f, q2 = 0.f;
#pragma unroll
    for (int mi = 0; mi < 4; ++mi)
#pragma unroll
      for (int r = 0; r < 4; ++r) {
        float v = acc[mi][ni][r];
        s += v;
        q2 = fmaf(v, v, q2);
      }
    cs[ni] = s;
    cq[ni] = q2;
  }
#pragma unroll
  for (int ni = 0; ni < 4; ++ni) {
    cs[ni] += __shfl_xor(cs[ni], 16);
    cs[ni] += __shfl_xor(cs[ni], 32);
    cq[ni] += __shfl_xor(cq[ni], 16);
    cq[ni] += __shfl_xor(cq[ni], 32);
  }
  float* sS = (float*)Asm;
  float* sQ = sS + 128;
  __syncthreads();
  if ((wv & 1) == 0 && g == 0) {
#pragma unroll
    for (int ni = 0; ni < 4; ++ni) {
      int col = wn + 16 * ni + lq;
      sS[col] = cs[ni];
      sQ[col] = cq[ni];
    }
  }
  __syncthreads();
  if ((wv & 1) == 1 && g == 0) {
#pragma unroll
    for (int ni = 0; ni < 4; ++ni) {
      int col = wn + 16 * ni + lq;
      sS[col] += cs[ni];
      sQ[col] += cq[ni];
    }
  }
  __syncthreads();
  if (tid < 128) {
    pS[(size_t)blockIdx.x * 256 + n0 + tid] = sS[tid];
    pSS[(size_t)blockIdx.x * 256 + n0 + tid] = sQ[tid];
  }
}

// ---------------------------------------------------------------------------
// MFMA attention + fused proj. P halved to 32-kv tiles (row stride 80B,
// padded, no swizzle) -> LDS 40KB. QK/PV interleaved per 32-kv half;
// accumulation order identical to R12 (bit-identical output).
// ---------------------------------------------------------------------------
__global__ __launch_bounds__(512) void attn_kernel(
    const u16* __restrict__ Qb, const u16* __restrict__ Kb,
    const u16* __restrict__ Vt, const int* __restrict__ routed,
    const u16* __restrict__ Wp, u16* __restrict__ XY) {
  __shared__ char Plds[40960];   // 8 waves x 64 q x 80B (32 kv bf16 + pad)
  int bn = blockIdx.x, b = bn >> 6, n = bn & 63;
  int h = threadIdx.x >> 6, l = threadIdx.x & 63;
  int lq = l & 15, g = l >> 4;
  char* Pw = Plds + h * 5120;

  const u16* Qrow = Qb + ((size_t)(b * 4096) + n * 64) * 256 + h * 32 + g * 8;
  s16x8 qf[4];
#pragma unroll
  for (int qi = 0; qi < 4; ++qi)
    qf[qi] = *(const s16x8*)(Qrow + (16 * qi + lq) * 256);

  f32x4 acc[4][2];
#pragma unroll
  for (int qi = 0; qi < 4; ++qi) {
    acc[qi][0] = (f32x4){0.f, 0.f, 0.f, 0.f};
    acc[qi][1] = (f32x4){0.f, 0.f, 0.f, 0.f};
  }
  float denom[4] = {0.f, 0.f, 0.f, 0.f};
  const f32x4 zero4 = {0.f, 0.f, 0.f, 0.f};
  const int* rptr = routed + bn * TOPK;

  for (int kk = 0; kk < TOPK; ++kk) {
    int pw = __builtin_amdgcn_readfirstlane(rptr[kk]);
    const u16* Krow = Kb + ((size_t)(b * 4096) + pw * 64) * 256 + h * 32 + g * 8;
    const u16* Vrow = Vt + ((size_t)(b * 256) + h * 32 + lq) * 4096 + pw * 64 + 8 * g;
#pragma unroll
    for (int half = 0; half < 2; ++half) {
#pragma unroll
      for (int kvil = 0; kvil < 2; ++kvil) {
        int kvi = half * 2 + kvil;
        s16x8 kf = *(const s16x8*)(Krow + (16 * kvi + lq) * 256);
        f32x4 sv[4];
#pragma unroll
        for (int qi = 0; qi < 4; ++qi)
          sv[qi] = MFMA(kf, qf[qi], zero4);
#pragma unroll
        for (int qi = 0; qi < 4; ++qi) {
          float p0 = __builtin_amdgcn_exp2f(sv[qi][0] * EXP2S);
          float p1 = __builtin_amdgcn_exp2f(sv[qi][1] * EXP2S);
          float p2 = __builtin_amdgcn_exp2f(sv[qi][2] * EXP2S);
          float p3 = __builtin_amdgcn_exp2f(sv[qi][3] * EXP2S);
          denom[qi] += (p0 + p1) + (p2 + p3);
          uint2 pk;
          pk.x = (unsigned)f2bf(p0) | ((unsigned)f2bf(p1) << 16);
          pk.y = (unsigned)f2bf(p2) | ((unsigned)f2bf(p3) << 16);
          int q = 16 * qi + lq;
          *(uint2*)(Pw + q * 80 + (16 * kvil + 4 * g) * 2) = pk;
        }
      }
      s16x8 vf[2];
#pragma unroll
      for (int di = 0; di < 2; ++di)
        vf[di] = *(const s16x8*)(Vrow + (size_t)(16 * di) * 4096 + 32 * half);
#pragma unroll
      for (int qi = 0; qi < 4; ++qi) {
        int q = 16 * qi + lq;
        s16x8 pf = *(const s16x8*)(Pw + q * 80 + 16 * g);
#pragma unroll
        for (int di = 0; di < 2; ++di)
          acc[qi][di] = MFMA(pf, vf[di], acc[qi][di]);
      }
    }
  }

#pragma unroll
  for (int qi = 0; qi < 4; ++qi) {
    denom[qi] += __shfl_xor(denom[qi], 16);
    denom[qi] += __shfl_xor(denom[qi], 32);
  }

  // --- write normalized O (bf16) into LDS tile [64 tok][256 ch], swizzled
  __syncthreads();   // all waves done reading their private P regions
  char* Ot = Plds;
#pragma unroll
  for (int qi = 0; qi < 4; ++qi) {
    float inv = 1.f / denom[qi];
#pragma unroll
    for (int r = 0; r < 4; ++r) {
      float nr = __shfl(inv, 4 * g + r);
      int t = 16 * qi + 4 * g + r;
      char* rowp = Ot + t * 512;
#pragma unroll
      for (int di = 0; di < 2; ++di) {
        int c = h * 32 + 16 * di + lq;
        *(u16*)(rowp + ((c * 2) ^ ((t & 7) << 4))) =
            f2bf(acc[qi][di][r] * nr);
      }
    }
  }
  __syncthreads();

  // --- fused proj: wave h computes Y cols [h*32, h*32+32), K=256 ascending
  f32x4 acc2[4][2];
#pragma unroll
  for (int mi = 0; mi < 4; ++mi) {
    acc2[mi][0] = (f32x4){0.f, 0.f, 0.f, 0.f};
    acc2[mi][1] = (f32x4){0.f, 0.f, 0.f, 0.f};
  }
#pragma unroll
  for (int k0 = 0; k0 < 256; k0 += 32) {
    s16x8 af[4], bfr[2];
#pragma unroll
    for (int mi = 0; mi < 4; ++mi) {
      int t = 16 * mi + lq;
      af[mi] = *(const s16x8*)(Ot + t * 512 +
                               (((k0 + 8 * g) * 2) ^ ((t & 7) << 4)));
    }
#pragma unroll
    for (int ni = 0; ni < 2; ++ni)
      bfr[ni] = *(const s16x8*)(Wp + (size_t)(h * 32 + 16 * ni + lq) * 256 +
                                k0 + 8 * g);
#pragma unroll
    for (int mi = 0; mi < 4; ++mi)
#pragma unroll
      for (int ni = 0; ni < 2; ++ni)
        acc2[mi][ni] = MFMA(af[mi], bfr[ni], acc2[mi][ni]);
  }

  u16* Yrow = XY + ((size_t)(b * 4096) + n * 64) * 512 + 256 + h * 32;
#pragma unroll
  for (int mi = 0; mi < 4; ++mi)
#pragma unroll
    for (int r = 0; r < 4; ++r) {
      u16* orow = Yrow + (size_t)(16 * mi + 4 * g + r) * 512 + lq;
#pragma unroll
      for (int ni = 0; ni < 2; ++ni)
        orow[16 * ni] = f2bf(acc2[mi][ni][r]);
    }
}

// ---------------------------------------------------------------------------
// BN finalize: sum 256 block-partials per channel -> scale/shift
// ---------------------------------------------------------------------------
__global__ __launch_bounds__(1024) void bnfin_kernel(
    const float* __restrict__ pS, const float* __restrict__ pSS,
    const float* __restrict__ gamma, const float* __restrict__ beta,
    float* __restrict__ scale, float* __restrict__ shift) {
  int tid = threadIdx.x;
  int c = tid >> 2, part = tid & 3;
  float S = 0.f, SS = 0.f;
  for (int m = part * 64; m < part * 64 + 64; ++m) {
    S += pS[m * 256 + c];
    SS += pSS[m * 256 + c];
  }
  __shared__ float rS[4][256], rQ[4][256];
  rS[part][c] = S;
  rQ[part][c] = SS;
  __syncthreads();
  if (tid < 256) {
    int cc = tid;
    float S2 = rS[0][cc] + rS[1][cc] + rS[2][cc] + rS[3][cc];
    float Q2 = rQ[0][cc] + rQ[1][cc] + rQ[2][cc] + rQ[3][cc];
    const float invN = 1.f / 32768.f;
    float mean = S2 * invN;
    float var = Q2 * invN - mean * mean;
    float sc = rsqrtf(var + 1e-5f) * gamma[cc];
    scale[cc] = sc;
    shift[cc] = beta[cc] - mean * sc;
  }
}

// ---------------------------------------------------------------------------
// final: block = (image row y, b). LDS-stage Y,G token-major; compute phase
// lane = pixel -> coalesced x/out.
// ---------------------------------------------------------------------------
__global__ __launch_bounds__(256) void final_kernel(
    const float* __restrict__ x, const u16* __restrict__ XY,
    const u16* __restrict__ GT, const float* __restrict__ scale,
    const float* __restrict__ shift, float* __restrict__ out) {
  __shared__ u16 Yl[64 * 256];
  __shared__ u16 Gl[64 * 256];
  __shared__ float sSc[256], sSh[256];
  int y = blockIdx.x, b = blockIdx.y;
  int tid = threadIdx.x;
  sSc[tid] = scale[tid];
  sSh[tid] = shift[tid];
  {
    int r = tid >> 2;
    int n = ((y >> 3) << 3) + (r >> 3);
    int t = ((y & 7) << 3) + (r & 7);
    size_t prow = (size_t)b * 4096 + n * 64 + t;
    const u16* ysrc = XY + prow * 512 + 256;
    const u16* gsrc = GT + prow * 256;
#pragma unroll
    for (int cc = 0; cc < 8; ++cc) {
      int chunk = (tid & 3) * 8 + cc;
      int off = r * 256 + ((chunk ^ (r & 31)) << 3);
      *(s16x8*)(Yl + off) = *(const s16x8*)(ysrc + chunk * 8);
      *(s16x8*)(Gl + off) = *(const s16x8*)(gsrc + chunk * 8);
    }
  }
  __syncthreads();
  int lane = tid & 63, wq = tid >> 6;
  size_t base = (size_t)(b * 256) * 4096 + y * 64 + lane;
#pragma unroll 2
  for (int ch = 0; ch < 8; ++ch) {
    int chunk = wq * 8 + ch;
    int off = lane * 256 + ((chunk ^ (lane & 31)) << 3);
    s16x8 yv = *(const s16x8*)(Yl + off);
    s16x8 gv = *(const s16x8*)(Gl + off);
#pragma unroll
    for (int j = 0; j < 8; ++j) {
      int c = chunk * 8 + j;
      size_t a = base + (size_t)c * 4096;
      float gate = 1.f / (1.f + __expf(-(fmaf(bf2f((u16)gv[j]), sSc[c], sSh[c]))));
      out[a] = x[a] + gate * bf2f((u16)yv[j]);
    }
  }
}

// ---------------------------------------------------------------------------
extern "C" void kernel_launch(void* const* d_in, const int* in_sizes, int n_in,
                              void* d_out, int out_size, void* d_ws, size_t ws_size,
                              hipStream_t stream) {
  const float* x      = (const float*)d_in[0];
  const float* prompt = (const float*)d_in[1];
  const float* Wq     = (const float*)d_in[2];
  const float* Wk     = (const float*)d_in[3];
  const float* Wv     = (const float*)d_in[4];
  const float* Wproj  = (const float*)d_in[5];
  const float* Wg     = (const float*)d_in[6];
  const float* gamma  = (const float*)d_in[7];
  const float* beta   = (const float*)d_in[8];

  char* wsb = (char*)d_ws;
  u16* XY    = (u16*)(wsb + 0);           // [b][p'][512]: x | y
  u16* PT    = (u16*)(wsb + 33554432);    // prompt [b][p'][256]
  u16* QT    = (u16*)(wsb + 50331648);    // Q [b][p'][256]  (aliases Pd, GT)
  u16* KT    = (u16*)(wsb + 67108864);    // K [b][p'][256]  (aliases pS/pSS)
  u16* VT    = (u16*)(wsb + 83886080);    // V channel-major [b*256+c][4096]
  u16* Wbf   = (u16*)(wsb + 117440512);   // Wq|Wk|Wv|Wproj|Wg bf16
  float* dx  = (float*)(wsb + 118226944);
  float* dp  = (float*)(wsb + 118751232);
  float* scl = (float*)(wsb + 119275520);
  float* shf = (float*)(wsb + 119276544);
  int* routed = (int*)(wsb + 119277568);
  float* Pd  = (float*)QT;                // 8MB, dead before qkv writes QT
  float* pS  = (float*)KT;                // 256KB, after attn (KT dead)
  float* pSS = (float*)(wsb + 67108864 + 262144);
  u16* GT = QT;                           // reuse: Q dead after attention

  pack_kernel<<<dim3(64, 16, 5), 256, 0, stream>>>(
      x, prompt, Wq, Wk, Wv, Wproj, Wg, XY, PT, Pd, Wbf);
  dred_kernel<<<dim3(16, 8), 256, 0, stream>>>(Pd, dx, dp);
  route_kernel<<<B * NW, 64, 0, stream>>>(dx, dp, routed);
  qkv_kernel<<<dim3(256, 6), 256, 0, stream>>>(XY, PT, Wbf, QT, KT, VT);
  attn_kernel<<<B * NW, 512, 0, stream>>>(QT, KT, VT, routed,
                                          Wbf + 196608, XY);
  gate_kernel<<<dim3(256, 2), 256, 0, stream>>>(XY, Wbf, GT, pS, pSS);
  bnfin_kernel<<<1, 1024, 0, stream>>>(pS, pSS, gamma, beta, scl, shf);
  final_kernel<<<dim3(64, 8), 256, 0, stream>>>(x, XY, GT, scl, shf, (float*)d_out);
}

// Round 19
// 156.583 us; speedup vs baseline: 2.0017x; 1.0101x over previous
//
#include <hip/hip_runtime.h>
#include <math.h>

#define B 8
#define Cc 256
#define P 4096
#define NW 64
#define NH 8
#define HD 32
#define TOPK 4
#define SCALE 0.17677669529663687f
#define EXP2S 0.2550348640579426f   // SCALE * log2(e)

typedef unsigned short u16;
typedef __attribute__((ext_vector_type(4))) float f32x4;
typedef __attribute__((ext_vector_type(8))) short s16x8;
typedef __attribute__((ext_vector_type(4))) unsigned short u16x4;

#define MFMA(a, b, c) __builtin_amdgcn_mfma_f32_16x16x32_bf16(a, b, c, 0, 0, 0)

__device__ inline u16 f2bf(float f) {
  unsigned u = __float_as_uint(f);
  return (u16)((u + 0x7fffu + ((u >> 16) & 1u)) >> 16);
}
__device__ inline float bf2f(u16 h) { return __uint_as_float(((unsigned)h) << 16); }

// ---------------------------------------------------------------------------
// pack v3 + fused weight-convert (blockIdx.z==4 plane)
// ---------------------------------------------------------------------------
__global__ __launch_bounds__(256) void pack_kernel(
    const float* __restrict__ x, const float* __restrict__ prompt,
    const float* __restrict__ Wq, const float* __restrict__ Wk,
    const float* __restrict__ Wv, const float* __restrict__ Wproj,
    const float* __restrict__ Wg,
    u16* __restrict__ XY, u16* __restrict__ PT, float* __restrict__ Pd,
    u16* __restrict__ Wbf) {
  if (blockIdx.z == 4) {
    int id = blockIdx.y * 64 + blockIdx.x;
    if (id >= 640) return;
    int job = id >> 7;
    const float* src;
    u16* dst;
    int n;
    switch (job) {
      case 0: src = Wq;    dst = Wbf;          n = 65536;  break;
      case 1: src = Wk;    dst = Wbf + 65536;  n = 65536;  break;
      case 2: src = Wv;    dst = Wbf + 131072; n = 65536;  break;
      case 3: src = Wproj; dst = Wbf + 196608; n = 65536;  break;
      default: src = Wg;   dst = Wbf + 262144; n = 131072; break;
    }
    int i = ((id & 127) * 256 + threadIdx.x) * 4;
    if (i < n) {
      float4 v = *(const float4*)(src + i);
      u16x4 o = {f2bf(v.x), f2bf(v.y), f2bf(v.z), f2bf(v.w)};
      *(u16x4*)(dst + i) = o;
    }
    return;
  }
  __shared__ u16 ldsd[64 * 68];
  __shared__ float pdl[64 * 9];
  int y = blockIdx.x;
  int sb = blockIdx.y;
  int cq = blockIdx.z;
  int sel = sb >> 3, b = sb & 7;
  const float* src =
      (sel ? prompt : x) + (size_t)(b * 256 + cq * 64) * 4096 + y * 64;
  int tid = threadIdx.x;
  int pxg = tid & 15;
  int cr = tid >> 4;
  int px0 = pxg * 4;
#pragma unroll
  for (int iter = 0; iter < 4; ++iter) {
    int cl = iter * 16 + cr;
    float4 v = *(const float4*)(src + (size_t)cl * 4096 + px0);
    u16x4 o = {f2bf(v.x), f2bf(v.y), f2bf(v.z), f2bf(v.w)};
    int sw = ((cl >> 3) & 3) << 2;
    *(u16x4*)(ldsd + cl * 68 + (px0 ^ sw)) = o;
    float s4 = (v.x + v.y) + (v.z + v.w);
    float s8 = s4 + __shfl_xor(s4, 1);
    if ((pxg & 1) == 0) pdl[cl * 9 + (pxg >> 1)] = s8;
  }
  __syncthreads();
  int tok = tid >> 2, cg = tid & 3;
  int n = ((y >> 3) << 3) + (tok >> 3);
  int tk = ((y & 7) << 3) + (tok & 7);
  size_t prow = (size_t)b * 4096 + n * 64 + tk;
  u16* dst = (sel ? (PT + prow * 256) : (XY + prow * 512)) + cq * 64;
#pragma unroll
  for (int cc = 0; cc < 2; ++cc) {
    int cb = cg * 8 + cc * 32;
    s16x8 v;
#pragma unroll
    for (int j = 0; j < 8; ++j) {
      int cl = cb + j;
      int sw = ((cl >> 3) & 3) << 2;
      v[j] = (short)ldsd[cl * 68 + (tok ^ sw)];
    }
    *(s16x8*)(dst + cb) = v;
  }
  float* pd = Pd + ((size_t)sb * 64 + y) * 2048 + cq * 64;
#pragma unroll
  for (int i = 0; i < 2; ++i) {
    int e = i * 256 + tid;
    int wx = e >> 6, cl = e & 63;
    pd[wx * 256 + cl] = pdl[cl * 9 + wx];
  }
}

// ---------------------------------------------------------------------------
// reduce partials -> descriptors [b][c][n] (f32, deterministic order)
// ---------------------------------------------------------------------------
__global__ __launch_bounds__(256) void dred_kernel(
    const float* __restrict__ Pd, float* __restrict__ dx, float* __restrict__ dp) {
  int sb = blockIdx.x;
  int sel = sb >> 3, b = sb & 7;
  int c = threadIdx.x;
  float* dst = (sel ? dp : dx) + ((size_t)b * 256 + c) * 64;
  const float* src = Pd + (size_t)sb * 64 * 2048;
#pragma unroll
  for (int nn = 0; nn < 8; ++nn) {
    int n = blockIdx.y * 8 + nn;
    int wy = n >> 3, wx = n & 7;
    float s = 0.f;
#pragma unroll
    for (int yl = 0; yl < 8; ++yl)
      s += src[((wy * 8 + yl) * 8 + wx) * 256 + c];
    dst[n] = s * (1.f / 64.f);
  }
}

// ---------------------------------------------------------------------------
// routing (f32, exact)
// ---------------------------------------------------------------------------
__global__ __launch_bounds__(64) void route_kernel(
    const float* __restrict__ dx, const float* __restrict__ dp,
    int* __restrict__ routed) {
  int bq = blockIdx.x;
  int b = bq >> 6;
  int q = bq & 63;
  int lane = threadIdx.x;
  const float* dxb = dx + (size_t)b * Cc * NW;
  const float* dpb = dp + (size_t)b * Cc * NW;
  float s = 0.f;
  for (int c = 0; c < Cc; ++c)
    s = fmaf(dxb[c * NW + q], dpb[c * NW + lane], s);
  s *= (1.f / 16.f);
  for (int kk = 0; kk < TOPK; ++kk) {
    float v = s;
    int i = lane;
    for (int off = 32; off; off >>= 1) {
      float ov = __shfl_xor(v, off);
      int oi = __shfl_xor(i, off);
      if (ov > v || (ov == v && oi < i)) { v = ov; i = oi; }
    }
    if (lane == 0) routed[bq * TOPK + kk] = i;
    if (lane == i) s = -INFINITY;
  }
}

// ---------------------------------------------------------------------------
// MFMA GEMM core 128x128xBK64, reg-staged (R5-proven structure)
// ---------------------------------------------------------------------------
__device__ __forceinline__ void gemm_core(
    const u16* __restrict__ A, int lda, const u16* __restrict__ W, int K,
    int m0, int n0, int tid, u16* Asm, u16* Wsm, f32x4 (&acc)[4][4]) {
  int l = tid & 63, wv = tid >> 6;
  int lq = l & 15, g = l >> 4;
  int wm = (wv & 1) * 64, wn = (wv >> 1) * 64;
  for (int k0 = 0; k0 < K; k0 += 64) {
    s16x8 av[4], wvv[4];
#pragma unroll
    for (int i = 0; i < 4; ++i) {
      int s = i * 256 + tid, row = s >> 3, u = s & 7;
      av[i] = *(const s16x8*)(A + (size_t)(m0 + row) * lda + k0 + u * 8);
      wvv[i] = *(const s16x8*)(W + (size_t)(n0 + row) * K + k0 + u * 8);
    }
    __syncthreads();
#pragma unroll
    for (int i = 0; i < 4; ++i) {
      int s = i * 256 + tid, row = s >> 3, u = s & 7;
      int gu = u ^ (row & 7);
      *(s16x8*)(Asm + row * 64 + gu * 8) = av[i];
      *(s16x8*)(Wsm + row * 64 + gu * 8) = wvv[i];
    }
    __syncthreads();
#pragma unroll
    for (int ks = 0; ks < 2; ++ks) {
      s16x8 af[4], bfr[4];
#pragma unroll
      for (int mi = 0; mi < 4; ++mi) {
        int r = wm + 16 * mi + lq;
        af[mi] = *(const s16x8*)(Asm + r * 64 + ((4 * ks + g) ^ (r & 7)) * 8);
      }
#pragma unroll
      for (int ni = 0; ni < 4; ++ni) {
        int r = wn + 16 * ni + lq;
        bfr[ni] = *(const s16x8*)(Wsm + r * 64 + ((4 * ks + g) ^ (r & 7)) * 8);
      }
#pragma unroll
      for (int mi = 0; mi < 4; ++mi)
#pragma unroll
        for (int ni = 0; ni < 4; ++ni)
          acc[mi][ni] = MFMA(af[mi], bfr[ni], acc[mi][ni]);
    }
  }
}

__device__ __forceinline__ void store_rowmajor(
    f32x4 (&acc)[4][4], u16* __restrict__ Out, int ldo,
    size_t mbase, int nbase, int lq, int g) {
#pragma unroll
  for (int mi = 0; mi < 4; ++mi) {
    size_t mrow = mbase + 16 * mi + 4 * g;
#pragma unroll
    for (int r = 0; r < 4; ++r) {
      u16* orow = Out + (mrow + r) * ldo + nbase + lq;
#pragma unroll
      for (int ni = 0; ni < 4; ++ni)
        orow[16 * ni] = f2bf(acc[mi][ni][r]);
    }
  }
}

__device__ __forceinline__ void store_chanmajor(
    f32x4 (&acc)[4][4], u16* __restrict__ Out,
    int bb, int tb, int cbase, int lq) {
#pragma unroll
  for (int ni = 0; ni < 4; ++ni) {
    u16* ocol = Out + ((size_t)(bb * 256) + cbase + 16 * ni + lq) * 4096 + tb;
#pragma unroll
    for (int mi = 0; mi < 4; ++mi) {
      u16x4 pk = {f2bf(acc[mi][ni][0]), f2bf(acc[mi][ni][1]),
                  f2bf(acc[mi][ni][2]), f2bf(acc[mi][ni][3])};
      *(u16x4*)(ocol + 16 * mi) = pk;
    }
  }
}

// ---------------------------------------------------------------------------
// Q/K/V in one launch: jy<2 -> Q (A=x part of XY); jy 2..5 -> K|V (A=PT)
// ---------------------------------------------------------------------------
__global__ __launch_bounds__(256) void qkv_kernel(
    const u16* __restrict__ XY, const u16* __restrict__ PT,
    const u16* __restrict__ Wbf, u16* __restrict__ QT,
    u16* __restrict__ KT, u16* __restrict__ VT) {
  __shared__ u16 Asm[8192], Wsm[8192];
  int jy = blockIdx.y, m0 = blockIdx.x * 128;
  int tid = threadIdx.x;
  int l = tid & 63, wv = tid >> 6;
  int lq = l & 15, g = l >> 4;
  int wm = (wv & 1) * 64, wn = (wv >> 1) * 64;
  f32x4 acc[4][4];
#pragma unroll
  for (int mi = 0; mi < 4; ++mi)
#pragma unroll
    for (int ni = 0; ni < 4; ++ni)
      acc[mi][ni] = (f32x4){0.f, 0.f, 0.f, 0.f};

  const u16* A;
  const u16* W;
  int lda, n0;
  if (jy < 2) { A = XY; lda = 512; W = Wbf; n0 = jy * 128; }
  else        { A = PT; lda = 256; W = Wbf + 65536; n0 = (jy - 2) * 128; }
  gemm_core(A, lda, W, 256, m0, n0, tid, Asm, Wsm, acc);

  if (jy < 2) {
    store_rowmajor(acc, QT, 256, (size_t)(m0 + wm), n0 + wn, lq, g);
  } else if (n0 < 256) {
    store_rowmajor(acc, KT, 256, (size_t)(m0 + wm), n0 + wn, lq, g);
  } else {
    store_chanmajor(acc, VT, m0 >> 12, (m0 & 4095) + wm + 4 * g,
                    (n0 - 256) + wn, lq);
  }
}

// ---------------------------------------------------------------------------
// gate: G = Wg * [x|y] (A=XY, K=512) + BN partial sums from f32 acc
// ---------------------------------------------------------------------------
__global__ __launch_bounds__(256) void gate_kernel(
    const u16* __restrict__ XY, const u16* __restrict__ Wbf,
    u16* __restrict__ GT, float* __restrict__ pS, float* __restrict__ pSS) {
  __shared__ u16 Asm[8192], Wsm[8192];
  int m0 = blockIdx.x * 128, n0 = blockIdx.y * 128;
  int tid = threadIdx.x;
  int l = tid & 63, wv = tid >> 6;
  int lq = l & 15, g = l >> 4;
  int wm = (wv & 1) * 64, wn = (wv >> 1) * 64;
  f32x4 acc[4][4];
#pragma unroll
  for (int mi = 0; mi < 4; ++mi)
#pragma unroll
    for (int ni = 0; ni < 4; ++ni)
      acc[mi][ni] = (f32x4){0.f, 0.f, 0.f, 0.f};
  gemm_core(XY, 512, Wbf + 262144, 512, m0, n0, tid, Asm, Wsm, acc);
  store_rowmajor(acc, GT, 256, (size_t)(m0 + wm), n0 + wn, lq, g);

  float cs[4], cq[4];
#pragma unroll
  for (int ni = 0; ni < 4; ++ni) {
    float s = 0.f, q2 = 0.f;
#pragma unroll
    for (int mi = 0; mi < 4; ++mi)
#pragma unroll
      for (int r = 0; r < 4; ++r) {
        float v = acc[mi][ni][r];
        s += v;
        q2 = fmaf(v, v, q2);
      }
    cs[ni] = s;
    cq[ni] = q2;
  }
#pragma unroll
  for (int ni = 0; ni < 4; ++ni) {
    cs[ni] += __shfl_xor(cs[ni], 16);
    cs[ni] += __shfl_xor(cs[ni], 32);
    cq[ni] += __shfl_xor(cq[ni], 16);
    cq[ni] += __shfl_xor(cq[ni], 32);
  }
  float* sS = (float*)Asm;
  float* sQ = sS + 128;
  __syncthreads();
  if ((wv & 1) == 0 && g == 0) {
#pragma unroll
    for (int ni = 0; ni < 4; ++ni) {
      int col = wn + 16 * ni + lq;
      sS[col] = cs[ni];
      sQ[col] = cq[ni];
    }
  }
  __syncthreads();
  if ((wv & 1) == 1 && g == 0) {
#pragma unroll
    for (int ni = 0; ni < 4; ++ni) {
      int col = wn + 16 * ni + lq;
      sS[col] += cs[ni];
      sQ[col] += cq[ni];
    }
  }
  __syncthreads();
  if (tid < 128) {
    pS[(size_t)blockIdx.x * 256 + n0 + tid] = sS[tid];
    pSS[(size_t)blockIdx.x * 256 + n0 + tid] = sQ[tid];
  }
}

// ---------------------------------------------------------------------------
// MFMA attention + fused proj (R15/R18 structure) + XCD-aware block swizzle:
// bn = (bid&7)*64 + bid>>3 puts all 64 query windows of batch i on XCD i,
// whose 4MB L2 then holds exactly batch i's K+V (4MB). Perf-only change.
// ---------------------------------------------------------------------------
__global__ __launch_bounds__(512) void attn_kernel(
    const u16* __restrict__ Qb, const u16* __restrict__ Kb,
    const u16* __restrict__ Vt, const int* __restrict__ routed,
    const u16* __restrict__ Wp, u16* __restrict__ XY) {
  __shared__ char Plds[40960];   // 8 waves x 64 q x 80B (32 kv bf16 + pad)
  int bid = blockIdx.x;
  int bn = ((bid & 7) << 6) + (bid >> 3);   // bijective: 512 % 8 == 0
  int b = bn >> 6, n = bn & 63;
  int h = threadIdx.x >> 6, l = threadIdx.x & 63;
  int lq = l & 15, g = l >> 4;
  char* Pw = Plds + h * 5120;

  const u16* Qrow = Qb + ((size_t)(b * 4096) + n * 64) * 256 + h * 32 + g * 8;
  s16x8 qf[4];
#pragma unroll
  for (int qi = 0; qi < 4; ++qi)
    qf[qi] = *(const s16x8*)(Qrow + (16 * qi + lq) * 256);

  f32x4 acc[4][2];
#pragma unroll
  for (int qi = 0; qi < 4; ++qi) {
    acc[qi][0] = (f32x4){0.f, 0.f, 0.f, 0.f};
    acc[qi][1] = (f32x4){0.f, 0.f, 0.f, 0.f};
  }
  float denom[4] = {0.f, 0.f, 0.f, 0.f};
  const f32x4 zero4 = {0.f, 0.f, 0.f, 0.f};
  const int* rptr = routed + bn * TOPK;

  for (int kk = 0; kk < TOPK; ++kk) {
    int pw = __builtin_amdgcn_readfirstlane(rptr[kk]);
    const u16* Krow = Kb + ((size_t)(b * 4096) + pw * 64) * 256 + h * 32 + g * 8;
    const u16* Vrow = Vt + ((size_t)(b * 256) + h * 32 + lq) * 4096 + pw * 64 + 8 * g;
#pragma unroll
    for (int half = 0; half < 2; ++half) {
#pragma unroll
      for (int kvil = 0; kvil < 2; ++kvil) {
        int kvi = half * 2 + kvil;
        s16x8 kf = *(const s16x8*)(Krow + (16 * kvi + lq) * 256);
        f32x4 sv[4];
#pragma unroll
        for (int qi = 0; qi < 4; ++qi)
          sv[qi] = MFMA(kf, qf[qi], zero4);
#pragma unroll
        for (int qi = 0; qi < 4; ++qi) {
          float p0 = __builtin_amdgcn_exp2f(sv[qi][0] * EXP2S);
          float p1 = __builtin_amdgcn_exp2f(sv[qi][1] * EXP2S);
          float p2 = __builtin_amdgcn_exp2f(sv[qi][2] * EXP2S);
          float p3 = __builtin_amdgcn_exp2f(sv[qi][3] * EXP2S);
          denom[qi] += (p0 + p1) + (p2 + p3);
          uint2 pk;
          pk.x = (unsigned)f2bf(p0) | ((unsigned)f2bf(p1) << 16);
          pk.y = (unsigned)f2bf(p2) | ((unsigned)f2bf(p3) << 16);
          int q = 16 * qi + lq;
          *(uint2*)(Pw + q * 80 + (16 * kvil + 4 * g) * 2) = pk;
        }
      }
      s16x8 vf[2];
#pragma unroll
      for (int di = 0; di < 2; ++di)
        vf[di] = *(const s16x8*)(Vrow + (size_t)(16 * di) * 4096 + 32 * half);
#pragma unroll
      for (int qi = 0; qi < 4; ++qi) {
        int q = 16 * qi + lq;
        s16x8 pf = *(const s16x8*)(Pw + q * 80 + 16 * g);
#pragma unroll
        for (int di = 0; di < 2; ++di)
          acc[qi][di] = MFMA(pf, vf[di], acc[qi][di]);
      }
    }
  }

#pragma unroll
  for (int qi = 0; qi < 4; ++qi) {
    denom[qi] += __shfl_xor(denom[qi], 16);
    denom[qi] += __shfl_xor(denom[qi], 32);
  }

  // --- write normalized O (bf16) into LDS tile [64 tok][256 ch], swizzled
  __syncthreads();   // all waves done reading their private P regions
  char* Ot = Plds;
#pragma unroll
  for (int qi = 0; qi < 4; ++qi) {
    float inv = 1.f / denom[qi];
#pragma unroll
    for (int r = 0; r < 4; ++r) {
      float nr = __shfl(inv, 4 * g + r);
      int t = 16 * qi + 4 * g + r;
      char* rowp = Ot + t * 512;
#pragma unroll
      for (int di = 0; di < 2; ++di) {
        int c = h * 32 + 16 * di + lq;
        *(u16*)(rowp + ((c * 2) ^ ((t & 7) << 4))) =
            f2bf(acc[qi][di][r] * nr);
      }
    }
  }
  __syncthreads();

  // --- fused proj: wave h computes Y cols [h*32, h*32+32), K=256 ascending
  f32x4 acc2[4][2];
#pragma unroll
  for (int mi = 0; mi < 4; ++mi) {
    acc2[mi][0] = (f32x4){0.f, 0.f, 0.f, 0.f};
    acc2[mi][1] = (f32x4){0.f, 0.f, 0.f, 0.f};
  }
#pragma unroll
  for (int k0 = 0; k0 < 256; k0 += 32) {
    s16x8 af[4], bfr[2];
#pragma unroll
    for (int mi = 0; mi < 4; ++mi) {
      int t = 16 * mi + lq;
      af[mi] = *(const s16x8*)(Ot + t * 512 +
                               (((k0 + 8 * g) * 2) ^ ((t & 7) << 4)));
    }
#pragma unroll
    for (int ni = 0; ni < 2; ++ni)
      bfr[ni] = *(const s16x8*)(Wp + (size_t)(h * 32 + 16 * ni + lq) * 256 +
                                k0 + 8 * g);
#pragma unroll
    for (int mi = 0; mi < 4; ++mi)
#pragma unroll
      for (int ni = 0; ni < 2; ++ni)
        acc2[mi][ni] = MFMA(af[mi], bfr[ni], acc2[mi][ni]);
  }

  u16* Yrow = XY + ((size_t)(b * 4096) + n * 64) * 512 + 256 + h * 32;
#pragma unroll
  for (int mi = 0; mi < 4; ++mi)
#pragma unroll
    for (int r = 0; r < 4; ++r) {
      u16* orow = Yrow + (size_t)(16 * mi + 4 * g + r) * 512 + lq;
#pragma unroll
      for (int ni = 0; ni < 2; ++ni)
        orow[16 * ni] = f2bf(acc2[mi][ni][r]);
    }
}

// ---------------------------------------------------------------------------
// BN finalize: sum 256 block-partials per channel -> scale/shift
// ---------------------------------------------------------------------------
__global__ __launch_bounds__(1024) void bnfin_kernel(
    const float* __restrict__ pS, const float* __restrict__ pSS,
    const float* __restrict__ gamma, const float* __restrict__ beta,
    float* __restrict__ scale, float* __restrict__ shift) {
  int tid = threadIdx.x;
  int c = tid >> 2, part = tid & 3;
  float S = 0.f, SS = 0.f;
  for (int m = part * 64; m < part * 64 + 64; ++m) {
    S += pS[m * 256 + c];
    SS += pSS[m * 256 + c];
  }
  __shared__ float rS[4][256], rQ[4][256];
  rS[part][c] = S;
  rQ[part][c] = SS;
  __syncthreads();
  if (tid < 256) {
    int cc = tid;
    float S2 = rS[0][cc] + rS[1][cc] + rS[2][cc] + rS[3][cc];
    float Q2 = rQ[0][cc] + rQ[1][cc] + rQ[2][cc] + rQ[3][cc];
    const float invN = 1.f / 32768.f;
    float mean = S2 * invN;
    float var = Q2 * invN - mean * mean;
    float sc = rsqrtf(var + 1e-5f) * gamma[cc];
    scale[cc] = sc;
    shift[cc] = beta[cc] - mean * sc;
  }
}

// ---------------------------------------------------------------------------
// final: block = (image row y, b). LDS-stage Y,G token-major; compute phase
// lane = pixel -> coalesced x/out.
// ---------------------------------------------------------------------------
__global__ __launch_bounds__(256) void final_kernel(
    const float* __restrict__ x, const u16* __restrict__ XY,
    const u16* __restrict__ GT, const float* __restrict__ scale,
    const float* __restrict__ shift, float* __restrict__ out) {
  __shared__ u16 Yl[64 * 256];
  __shared__ u16 Gl[64 * 256];
  __shared__ float sSc[256], sSh[256];
  int y = blockIdx.x, b = blockIdx.y;
  int tid = threadIdx.x;
  sSc[tid] = scale[tid];
  sSh[tid] = shift[tid];
  {
    int r = tid >> 2;
    int n = ((y >> 3) << 3) + (r >> 3);
    int t = ((y & 7) << 3) + (r & 7);
    size_t prow = (size_t)b * 4096 + n * 64 + t;
    const u16* ysrc = XY + prow * 512 + 256;
    const u16* gsrc = GT + prow * 256;
#pragma unroll
    for (int cc = 0; cc < 8; ++cc) {
      int chunk = (tid & 3) * 8 + cc;
      int off = r * 256 + ((chunk ^ (r & 31)) << 3);
      *(s16x8*)(Yl + off) = *(const s16x8*)(ysrc + chunk * 8);
      *(s16x8*)(Gl + off) = *(const s16x8*)(gsrc + chunk * 8);
    }
  }
  __syncthreads();
  int lane = tid & 63, wq = tid >> 6;
  size_t base = (size_t)(b * 256) * 4096 + y * 64 + lane;
#pragma unroll 2
  for (int ch = 0; ch < 8; ++ch) {
    int chunk = wq * 8 + ch;
    int off = lane * 256 + ((chunk ^ (lane & 31)) << 3);
    s16x8 yv = *(const s16x8*)(Yl + off);
    s16x8 gv = *(const s16x8*)(Gl + off);
#pragma unroll
    for (int j = 0; j < 8; ++j) {
      int c = chunk * 8 + j;
      size_t a = base + (size_t)c * 4096;
      float gate = 1.f / (1.f + __expf(-(fmaf(bf2f((u16)gv[j]), sSc[c], sSh[c]))));
      out[a] = x[a] + gate * bf2f((u16)yv[j]);
    }
  }
}

// ---------------------------------------------------------------------------
extern "C" void kernel_launch(void* const* d_in, const int* in_sizes, int n_in,
                              void* d_out, int out_size, void* d_ws, size_t ws_size,
                              hipStream_t stream) {
  const float* x      = (const float*)d_in[0];
  const float* prompt = (const float*)d_in[1];
  const float* Wq     = (const float*)d_in[2];
  const float* Wk     = (const float*)d_in[3];
  const float* Wv     = (const float*)d_in[4];
  const float* Wproj  = (const float*)d_in[5];
  const float* Wg     = (const float*)d_in[6];
  const float* gamma  = (const float*)d_in[7];
  const float* beta   = (const float*)d_in[8];

  char* wsb = (char*)d_ws;
  u16* XY    = (u16*)(wsb + 0);           // [b][p'][512]: x | y
  u16* PT    = (u16*)(wsb + 33554432);    // prompt [b][p'][256]
  u16* QT    = (u16*)(wsb + 50331648);    // Q [b][p'][256]  (aliases Pd, GT)
  u16* KT    = (u16*)(wsb + 67108864);    // K [b][p'][256]  (aliases pS/pSS)
  u16* VT    = (u16*)(wsb + 83886080);    // V channel-major [b*256+c][4096]
  u16* Wbf   = (u16*)(wsb + 117440512);   // Wq|Wk|Wv|Wproj|Wg bf16
  float* dx  = (float*)(wsb + 118226944);
  float* dp  = (float*)(wsb + 118751232);
  float* scl = (float*)(wsb + 119275520);
  float* shf = (float*)(wsb + 119276544);
  int* routed = (int*)(wsb + 119277568);
  float* Pd  = (float*)QT;                // 8MB, dead before qkv writes QT
  float* pS  = (float*)KT;                // 256KB, after attn (KT dead)
  float* pSS = (float*)(wsb + 67108864 + 262144);
  u16* GT = QT;                           // reuse: Q dead after attention

  pack_kernel<<<dim3(64, 16, 5), 256, 0, stream>>>(
      x, prompt, Wq, Wk, Wv, Wproj, Wg, XY, PT, Pd, Wbf);
  dred_kernel<<<dim3(16, 8), 256, 0, stream>>>(Pd, dx, dp);
  route_kernel<<<B * NW, 64, 0, stream>>>(dx, dp, routed);
  qkv_kernel<<<dim3(256, 6), 256, 0, stream>>>(XY, PT, Wbf, QT, KT, VT);
  attn_kernel<<<B * NW, 512, 0, stream>>>(QT, KT, VT, routed,
                                          Wbf + 196608, XY);
  gate_kernel<<<dim3(256, 2), 256, 0, stream>>>(XY, Wbf, GT, pS, pSS);
  bnfin_kernel<<<1, 1024, 0, stream>>>(pS, pSS, gamma, beta, scl, shf);
  final_kernel<<<dim3(64, 8), 256, 0, stream>>>(x, XY, GT, scl, shf, (float*)d_out);
}